// Round 1
// baseline (8270.515 us; speedup 1.0000x reference)
//
#include <hip/hip_runtime.h>

// Sizes fixed by the problem: V=5000, C=128, K=64, N=K*K=4096.
#define NV 5000
#define NC 128
#define NK 64
#define NN 4096
#define LMBDA 100.0f

// workspace layout (float offsets)
#define A_OFF    0
#define B0_OFF   8192
#define BC_OFF   16384
#define X_OFF    24576
#define R1R_OFF  28672
#define R1I_OFF  28736
#define R2R_OFF  28800
#define R2I_OFF  28864
#define G_OFF    28928
#define H_OFF    33024
#define S0_OFF   37120
#define S1R_OFF  41216
#define S1I_OFF  45312
#define S2_OFF   49408
#define W0_OFF   53504
#define Z_OFF    57600
#define RM_OFF   61696
#define Y_OFF    65792
#define WV_OFF   69888
#define FLAG_OFF 73984   // 128 ints (fwd 64 + bwd 64)
#define TG_OFF   74112
#define OP_OFF   131072
#define TMAGIC   0x13579B

// ---------------- A = Px@fx, B0 = Py@fy  ([64,5000]@[5000,128]) ----------------
__global__ __launch_bounds__(128) void proj_kernel(const float* Px, const float* fx,
                                                   const float* Py, const float* fy,
                                                   float* A, float* B0) {
  int row = blockIdx.x, c = threadIdx.x;
  const float* P = blockIdx.y ? Py : Px;
  const float* f = blockIdx.y ? fy : fx;
  float* o = blockIdx.y ? B0 : A;
  const float* pr = P + row * NV;
  float a0 = 0.f, a1 = 0.f, a2 = 0.f, a3 = 0.f;
  for (int v = 0; v < NV; v += 4) {
    a0 = fmaf(pr[v + 0], f[(v + 0) * NC + c], a0);
    a1 = fmaf(pr[v + 1], f[(v + 1) * NC + c], a1);
    a2 = fmaf(pr[v + 2], f[(v + 2) * NC + c], a2);
    a3 = fmaf(pr[v + 3], f[(v + 3) * NC + c], a3);
  }
  o[row * NC + c] = (a0 + a1) + (a2 + a3);
}

// ---------------- X = inv(Mx) via Gauss-Jordan w/ partial pivoting ----------------
__global__ __launch_bounds__(256) void invert_kernel(const float* Mx, float* X) {
  __shared__ float M[64][130];
  __shared__ float mult[64];
  __shared__ int piv;
  int tid = threadIdx.x;
  for (int e = tid; e < 4096; e += 256) {
    int r = e >> 6, c = e & 63;
    M[r][c] = Mx[e];
    M[r][64 + c] = (r == c) ? 1.f : 0.f;
  }
  __syncthreads();
  for (int k = 0; k < 64; ++k) {
    if (tid == 0) {
      int best = k; float bv = fabsf(M[k][k]);
      for (int r = k + 1; r < 64; ++r) { float v = fabsf(M[r][k]); if (v > bv) { bv = v; best = r; } }
      piv = best;
    }
    __syncthreads();
    if (piv != k) {
      for (int c = tid; c < 128; c += 256) { float t = M[k][c]; M[k][c] = M[piv][c]; M[piv][c] = t; }
    }
    __syncthreads();
    float pv = M[k][k];
    __syncthreads();
    float d = 1.f / pv;
    for (int c = tid; c < 128; c += 256) M[k][c] *= d;
    if (tid < 64) mult[tid] = (tid == k) ? 0.f : M[tid][k];
    __syncthreads();
    for (int e = tid; e < 8192; e += 256) {
      int r = e >> 7, c = e & 127;
      M[r][c] = fmaf(-mult[r], M[k][c], M[r][c]);
    }
    __syncthreads();
  }
  for (int e = tid; e < 4096; e += 256) X[e] = M[e >> 6][64 + (e & 63)];
}

// ---------------- resolvent scalar vectors ----------------
__global__ void scal_kernel(const float* ex, const float* ey,
                            float* r1r, float* r1i, float* r2r, float* r2i) {
  int t = threadIdx.x;  // 64 threads = 1 wave
  float vx = ex[t], vy = ey[t];
  float m = fmaxf(vx, vy);
#pragma unroll
  for (int o = 32; o > 0; o >>= 1) m = fmaxf(m, __shfl_xor(m, o, 64));
  float g1 = sqrtf(vx / m), g2 = sqrtf(vy / m);   // GAMMA = 0.5
  float d1 = 1.f / fmaf(g1, g1, 1.f), d2 = 1.f / fmaf(g2, g2, 1.f);
  r1r[t] = g1 * d1; r1i[t] = d1;
  r2r[t] = g2 * d2; r2i[t] = d2;
}

// ---------------- Bc = My @ B0 ----------------
__global__ __launch_bounds__(256) void bc_kernel(const float* My, const float* B0, float* Bc) {
  int idx = blockIdx.x * 256 + threadIdx.x;
  int i = idx >> 7, c = idx & 127;
  float acc = 0.f;
  for (int j = 0; j < 64; ++j) acc = fmaf(My[i * 64 + j], B0[j * NC + c], acc);
  Bc[idx] = acc;
}

// ---------------- small 64x64 products ----------------
__global__ __launch_bounds__(256) void smallmm_kernel(const float* A, const float* My, const float* X,
                                                      const float* r1r, const float* r1i, const float* Bc,
                                                      float* G, float* H, float* S0l, float* S1rl,
                                                      float* S1il, float* S2, float* Z) {
  int idx = blockIdx.x * 256 + threadIdx.x;
  int i = idx >> 6, j = idx & 63;
  int q = blockIdx.y;
  float acc = 0.f;
  if (q == 0) { for (int c = 0; c < 128; ++c) acc = fmaf(A[i * NC + c], A[j * NC + c], acc); G[idx] = acc; }
  else if (q == 1) { for (int t = 0; t < 64; ++t) acc = fmaf(My[t * 64 + i], My[t * 64 + j], acc); H[idx] = acc; }
  else if (q == 2) { for (int t = 0; t < 64; ++t) acc = fmaf(X[t * 64 + i], X[t * 64 + j], acc); S0l[idx] = LMBDA * acc; }
  else if (q == 3) { for (int t = 0; t < 64; ++t) acc = fmaf(r1r[t] * X[t * 64 + i], X[t * 64 + j], acc); S1rl[idx] = LMBDA * acc; }
  else if (q == 4) { for (int t = 0; t < 64; ++t) acc = fmaf(r1i[t] * X[t * 64 + i], X[t * 64 + j], acc); S1il[idx] = LMBDA * acc; }
  else if (q == 5) { for (int t = 0; t < 64; ++t) { float w2 = fmaf(r1r[t], r1r[t], r1i[t] * r1i[t]); acc = fmaf(w2 * X[t * 64 + i], X[t * 64 + j], acc); } S2[idx] = acc; }
  else { for (int c = 0; c < 128; ++c) acc = fmaf(A[i * NC + c], Bc[j * NC + c], acc); Z[idx] = acc; }
}

// ---------------- Rm = Z@My (rhs), W0 = G + lambda*S2 ----------------
__global__ __launch_bounds__(256) void rmw_kernel(const float* Z, const float* My, const float* G,
                                                  const float* S2, float* Rm, float* W0) {
  int idx = blockIdx.x * 256 + threadIdx.x;
  int i = idx >> 6, j = idx & 63;
  float acc = 0.f;
  for (int t = 0; t < 64; ++t) acc = fmaf(Z[i * 64 + t], My[t * 64 + j], acc);
  Rm[idx] = acc;
  W0[idx] = fmaf(LMBDA, S2[idx], G[idx]);
}

// ---------------- materialize op[4096][4096] from Kronecker structure ----------------
__global__ __launch_bounds__(256) void buildop_kernel(const float* H, const float* W0, const float* S0l,
                                                      const float* S1rl, const float* S1il,
                                                      const float* r2r, const float* r2i, float* op) {
  int R = blockIdx.x;
  int i1 = R >> 6, i2 = R & 63;
  int cb = (blockIdx.y * 256 + threadIdx.x) * 4;
  int j1 = cb >> 6, j2 = cb & 63;
  float w0 = W0[i1 * 64 + j1], s0 = S0l[i1 * 64 + j1];
  float s1r = S1rl[i1 * 64 + j1], s1i = S1il[i1 * 64 + j1];
  float a2 = r2r[i2], b2 = r2i[i2];
  float4 h = *(const float4*)(H + i2 * 64 + j2);
  float4 ar = *(const float4*)(r2r + j2);
  float4 ai = *(const float4*)(r2i + j2);
  float4 o;
  o.x = h.x * (w0 + (a2 * ar.x + b2 * ai.x) * s0 - (a2 + ar.x) * s1r - (b2 + ai.x) * s1i);
  o.y = h.y * (w0 + (a2 * ar.y + b2 * ai.y) * s0 - (a2 + ar.y) * s1r - (b2 + ai.y) * s1i);
  o.z = h.z * (w0 + (a2 * ar.z + b2 * ai.z) * s0 - (a2 + ar.z) * s1r - (b2 + ai.z) * s1i);
  o.w = h.w * (w0 + (a2 * ar.w + b2 * ai.w) * s0 - (a2 + ar.w) * s1r - (b2 + ai.w) * s1i);
  *(float4*)(op + (size_t)R * NN + cb) = o;
}

// ---------------- Cholesky: diag 64x64 factor + inverse of L11 ----------------
__global__ __launch_bounds__(256) void potrf_kernel(float* op, float* Tg, int p) {
  __shared__ float M[64][65];
  __shared__ float T[64][65];
  int tid = threadIdx.x;
  int d0 = p * 64;
  for (int e = tid; e < 4096; e += 256) {
    int r = e >> 6, c = e & 63;
    M[r][c] = op[((size_t)(d0 + r)) * NN + d0 + c];
    T[r][c] = 0.f;
  }
  __syncthreads();
  for (int j = 0; j < 64; ++j) {
    float pv = M[j][j];
    __syncthreads();
    float sc = rsqrtf(pv);
    if (tid < 64 - j) M[j + tid][j] *= sc;
    __syncthreads();
    int m = 63 - j, cnt = (m * (m + 1)) >> 1;
    for (int e = tid; e < cnt; e += 256) {
      int rp = (int)((sqrtf(8.f * (float)e + 1.f) - 1.f) * 0.5f);
      while (((rp + 1) * (rp + 2)) >> 1 <= e) ++rp;
      while ((rp * (rp + 1)) >> 1 > e) --rp;
      int cp = e - ((rp * (rp + 1)) >> 1);
      int r = j + 1 + rp, c = j + 1 + cp;
      M[r][c] = fmaf(-M[r][j], M[c][j], M[r][c]);
    }
    __syncthreads();
  }
  if (tid < 64) {               // Tinv = L11^{-1}, one lane per column
    int c = tid;
    T[c][c] = 1.f / M[c][c];
    for (int r = c + 1; r < 64; ++r) {
      float s = 0.f;
      for (int t = c; t < r; ++t) s = fmaf(M[r][t], T[t][c], s);
      T[r][c] = -s / M[r][r];
    }
  }
  __syncthreads();
  for (int e = tid; e < 4096; e += 256) {
    int r = e >> 6, c = e & 63;
    if (c <= r) op[((size_t)(d0 + r)) * NN + d0 + c] = M[r][c];
    Tg[e] = T[r][c];
  }
}

// ---------------- panel trsm as GEMM: L21 = A21 * Tinv^T ----------------
__global__ __launch_bounds__(256) void trsm_kernel(float* op, const float* Tg, int p) {
  int d0 = p * 64;
  size_t r0 = (size_t)d0 + 64 + (size_t)blockIdx.x * 64;
  __shared__ __align__(16) float As[64][68];
  __shared__ __align__(16) float Ts[64][68];
  int tid = threadIdx.x;
  for (int e = tid; e < 4096; e += 256) {
    int r = e >> 6, t = e & 63;
    As[t][r] = op[(r0 + r) * NN + d0 + t];
    Ts[t][r] = Tg[r * 64 + t];
  }
  __syncthreads();
  int ty = tid >> 4, tx = tid & 15;
  float acc[4][4] = {};
  for (int t = 0; t < 64; ++t) {
    float4 a4 = *(const float4*)&As[t][ty * 4];
    float4 b4 = *(const float4*)&Ts[t][tx * 4];
    float a[4] = {a4.x, a4.y, a4.z, a4.w};
    float b[4] = {b4.x, b4.y, b4.z, b4.w};
#pragma unroll
    for (int u = 0; u < 4; ++u)
#pragma unroll
      for (int v = 0; v < 4; ++v) acc[u][v] = fmaf(a[u], b[v], acc[u][v]);
  }
  __syncthreads();
#pragma unroll
  for (int u = 0; u < 4; ++u) {
    float4 o = make_float4(acc[u][0], acc[u][1], acc[u][2], acc[u][3]);
    *(float4*)(op + (r0 + ty * 4 + u) * NN + d0 + tx * 4) = o;
  }
}

// ---------------- trailing update: C -= L21_i * L21_j^T (lower-tri tiles) ----------------
__global__ __launch_bounds__(256) void syrk_kernel(float* op, int p) {
  int b = blockIdx.x;
  int bi = (int)((sqrtf(8.f * (float)b + 1.f) - 1.f) * 0.5f);
  while ((bi + 1) * (bi + 2) / 2 <= b) ++bi;
  while (bi * (bi + 1) / 2 > b) --bi;
  int bj = b - bi * (bi + 1) / 2;
  int d0 = p * 64;
  size_t r0 = (size_t)d0 + 64 + (size_t)bi * 64;
  size_t c0 = (size_t)d0 + 64 + (size_t)bj * 64;
  __shared__ __align__(16) float Ab[64][68];
  __shared__ __align__(16) float Bb[64][68];
  int tid = threadIdx.x;
  for (int e = tid; e < 4096; e += 256) {
    int r = e >> 6, k = e & 63;
    Ab[k][r] = op[(r0 + r) * NN + d0 + k];
    Bb[k][r] = op[(c0 + r) * NN + d0 + k];
  }
  __syncthreads();
  int ty = tid >> 4, tx = tid & 15;
  float acc[4][4] = {};
  for (int k = 0; k < 64; ++k) {
    float4 a4 = *(const float4*)&Ab[k][ty * 4];
    float4 b4 = *(const float4*)&Bb[k][tx * 4];
    float a[4] = {a4.x, a4.y, a4.z, a4.w};
    float b[4] = {b4.x, b4.y, b4.z, b4.w};
#pragma unroll
    for (int u = 0; u < 4; ++u)
#pragma unroll
      for (int v = 0; v < 4; ++v) acc[u][v] = fmaf(a[u], b[v], acc[u][v]);
  }
#pragma unroll
  for (int u = 0; u < 4; ++u) {
    float* dst = op + (r0 + ty * 4 + u) * NN + c0 + tx * 4;
    float4 cur = *(const float4*)dst;
    cur.x -= acc[u][0]; cur.y -= acc[u][1]; cur.z -= acc[u][2]; cur.w -= acc[u][3];
    *(float4*)dst = cur;
  }
}

__global__ void initflags_kernel(int* f) { f[threadIdx.x] = 0; }  // 128 threads

// ---------------- pipelined triangular solve (64 blocks, spin flags) ----------------
__global__ __launch_bounds__(256) void trisolve_kernel(const float* op, const float* bvec, float* x,
                                                       int* flags, int backward) {
  int tid = threadIdx.x;
  int s = backward ? (63 - (int)blockIdx.x) : (int)blockIdx.x;
  __shared__ float Ld[64][65];
  __shared__ float red[256];
  for (int e = tid; e < 4096; e += 256) {
    int r = e >> 6, c = e & 63;
    Ld[r][c] = op[((size_t)(64 * s + r)) * NN + 64 * s + c];
  }
  int g, q;
  if (!backward) { g = tid >> 2; q = tid & 3; } else { g = tid & 63; q = tid >> 6; }
  float part = 0.f;
  int nsteps = backward ? (63 - s) : s;
  for (int st = 0; st < nsteps; ++st) {
    int t = backward ? (63 - st) : st;
    float tl[16];
    if (!backward) {
      const float4* src = (const float4*)(op + ((size_t)(64 * s + g)) * NN + 64 * t + q * 16);
      float4 v0 = src[0], v1 = src[1], v2 = src[2], v3 = src[3];
      tl[0] = v0.x; tl[1] = v0.y; tl[2] = v0.z; tl[3] = v0.w;
      tl[4] = v1.x; tl[5] = v1.y; tl[6] = v1.z; tl[7] = v1.w;
      tl[8] = v2.x; tl[9] = v2.y; tl[10] = v2.z; tl[11] = v2.w;
      tl[12] = v3.x; tl[13] = v3.y; tl[14] = v3.z; tl[15] = v3.w;
    } else {
#pragma unroll
      for (int u = 0; u < 16; ++u)
        tl[u] = op[((size_t)(64 * t + q * 16 + u)) * NN + 64 * s + g];
    }
    if (tid == 0) {
      while (__hip_atomic_load(&flags[t], __ATOMIC_ACQUIRE, __HIP_MEMORY_SCOPE_AGENT) != TMAGIC) {}
    }
    __syncthreads();
    const float* xt = x + 64 * t;
#pragma unroll
    for (int u = 0; u < 16; ++u) {
      float xv = __hip_atomic_load(xt + q * 16 + u, __ATOMIC_RELAXED, __HIP_MEMORY_SCOPE_AGENT);
      part = fmaf(tl[u], xv, part);
    }
  }
  red[tid] = part;
  __syncthreads();
  if (tid < 64) {
    float cross;
    if (!backward) cross = red[tid * 4 + 0] + red[tid * 4 + 1] + red[tid * 4 + 2] + red[tid * 4 + 3];
    else cross = red[tid] + red[64 + tid] + red[128 + tid] + red[192 + tid];
    float acc = bvec[64 * s + tid] - cross;
    float invd = 1.f / Ld[tid][tid];
    float myx = 0.f;
    if (!backward) {
      for (int c = 0; c < 64; ++c) {
        float xc = __shfl(acc, c, 64) * __shfl(invd, c, 64);
        if (tid > c) acc = fmaf(-Ld[tid][c], xc, acc);
        if (tid == c) myx = xc;
      }
    } else {
      for (int c = 63; c >= 0; --c) {
        float xc = __shfl(acc, c, 64) * __shfl(invd, c, 64);
        if (tid < c) acc = fmaf(-Ld[c][tid], xc, acc);
        if (tid == c) myx = xc;
      }
    }
    __hip_atomic_store(&x[64 * s + tid], myx, __ATOMIC_RELAXED, __HIP_MEMORY_SCOPE_AGENT);
  }
  __threadfence();
  __syncthreads();
  if (tid == 0) __hip_atomic_store(&flags[s], TMAGIC, __ATOMIC_RELEASE, __HIP_MEMORY_SCOPE_AGENT);
}

// ---------------- C = W^T ----------------
__global__ void out_kernel(const float* wv, float* out) {
  int e = blockIdx.x * 256 + threadIdx.x;
  out[e] = wv[(e & 63) * 64 + (e >> 6)];
}

extern "C" void kernel_launch(void* const* d_in, const int* in_sizes, int n_in,
                              void* d_out, int out_size, void* d_ws, size_t ws_size,
                              hipStream_t stream) {
  const float* fx = (const float*)d_in[0];
  const float* fy = (const float*)d_in[1];
  const float* ex = (const float*)d_in[2];
  const float* ey = (const float*)d_in[3];
  const float* Px = (const float*)d_in[4];
  const float* Py = (const float*)d_in[5];
  const float* Mx = (const float*)d_in[6];
  const float* My = (const float*)d_in[7];
  float* out = (float*)d_out;
  float* W = (float*)d_ws;

  size_t need = ((size_t)OP_OFF + (size_t)NN * NN) * sizeof(float);
  if (ws_size < need) {  // clean failure signal if workspace too small
    hipMemsetAsync(d_out, 0, (size_t)out_size * sizeof(float), stream);
    return;
  }

  float* Ap = W + A_OFF;   float* B0 = W + B0_OFF;  float* Bc = W + BC_OFF;
  float* Xp = W + X_OFF;
  float* r1r = W + R1R_OFF; float* r1i = W + R1I_OFF;
  float* r2r = W + R2R_OFF; float* r2i = W + R2I_OFF;
  float* G = W + G_OFF;    float* H = W + H_OFF;
  float* S0l = W + S0_OFF; float* S1rl = W + S1R_OFF; float* S1il = W + S1I_OFF;
  float* S2 = W + S2_OFF;  float* W0 = W + W0_OFF;
  float* Z = W + Z_OFF;    float* Rm = W + RM_OFF;
  float* Yv = W + Y_OFF;   float* Wv = W + WV_OFF;
  int* flagF = (int*)(W + FLAG_OFF);
  int* flagB = flagF + 64;
  float* Tg = W + TG_OFF;
  float* op = W + OP_OFF;

  dim3 gProj(64, 2);
  proj_kernel<<<gProj, 128, 0, stream>>>(Px, fx, Py, fy, Ap, B0);
  invert_kernel<<<1, 256, 0, stream>>>(Mx, Xp);
  scal_kernel<<<1, 64, 0, stream>>>(ex, ey, r1r, r1i, r2r, r2i);
  bc_kernel<<<32, 256, 0, stream>>>(My, B0, Bc);
  dim3 gSm(16, 7);
  smallmm_kernel<<<gSm, 256, 0, stream>>>(Ap, My, Xp, r1r, r1i, Bc, G, H, S0l, S1rl, S1il, S2, Z);
  rmw_kernel<<<16, 256, 0, stream>>>(Z, My, G, S2, Rm, W0);
  dim3 gOp(4096, 4);
  buildop_kernel<<<gOp, 256, 0, stream>>>(H, W0, S0l, S1rl, S1il, r2r, r2i, op);

  for (int p = 0; p < 64; ++p) {
    potrf_kernel<<<1, 256, 0, stream>>>(op, Tg, p);
    int nt = 63 - p;
    if (nt > 0) {
      trsm_kernel<<<nt, 256, 0, stream>>>(op, Tg, p);
      syrk_kernel<<<nt * (nt + 1) / 2, 256, 0, stream>>>(op, p);
    }
  }

  initflags_kernel<<<1, 128, 0, stream>>>(flagF);
  trisolve_kernel<<<64, 256, 0, stream>>>(op, Rm, Yv, flagF, 0);
  trisolve_kernel<<<64, 256, 0, stream>>>(op, Yv, Wv, flagB, 1);
  out_kernel<<<16, 256, 0, stream>>>(Wv, out);
}

// Round 2
// 813.767 us; speedup vs baseline: 10.1633x; 10.1633x over previous
//
#include <hip/hip_runtime.h>

// Sizes fixed by the problem: V=5000, C=128, K=64, N=K*K=4096.
#define NV 5000
#define NC 128
#define NN 4096
#define LMBDA 100.0f
#define MAXIT 320

// workspace layout (float offsets)
#define A_OFF    0
#define B0_OFF   8192
#define BC_OFF   16384
#define X_OFF    24576
#define R1R_OFF  28672
#define R1I_OFF  28736
#define R2R_OFF  28800
#define R2I_OFF  28864
#define G_OFF    28928
#define H_OFF    33024
#define S0_OFF   37120
#define S1R_OFF  41216
#define S1I_OFF  45312
#define S2_OFF   49408
#define W0_OFF   53504
#define Z_OFF    57600
#define RM_OFF   61696
#define Q0_OFF   65792
#define QR_OFF   69888
#define QI_OFF   73984
#define LWI_OFF  78080
#define LHI_OFF  82176
#define ST0_OFF  86272
#define ST1R_OFF 90368
#define ST1I_OFF 94464
#define QT0_OFF  98560
#define QTR_OFF  102656
#define QTI_OFF  106752
#define BT_OFF   110848
#define RSTK_OFF 114944
#define LCT_OFF  131328
#define RG_OFF   147712
#define YG_OFF   151808
#define CNT_OFF  155904
#define PQ_OFF   155968
#define RR_OFF   156288
#define WS_NEED  157952

__device__ __forceinline__ float aload(const float* p) {
  return __hip_atomic_load(p, __ATOMIC_RELAXED, __HIP_MEMORY_SCOPE_AGENT);
}
__device__ __forceinline__ void astore(float* p, float v) {
  __hip_atomic_store(p, v, __ATOMIC_RELAXED, __HIP_MEMORY_SCOPE_AGENT);
}

// ---------------- A = Px@fx, B0 = Py@fy  ([64,5000]@[5000,128]) ----------------
__global__ __launch_bounds__(128) void proj_kernel(const float* Px, const float* fx,
                                                   const float* Py, const float* fy,
                                                   float* A, float* B0) {
  int row = blockIdx.x, c = threadIdx.x;
  const float* P = blockIdx.y ? Py : Px;
  const float* f = blockIdx.y ? fy : fx;
  float* o = blockIdx.y ? B0 : A;
  const float* pr = P + row * NV;
  float a0 = 0.f, a1 = 0.f, a2 = 0.f, a3 = 0.f;
  for (int v = 0; v < NV; v += 4) {
    a0 = fmaf(pr[v + 0], f[(v + 0) * NC + c], a0);
    a1 = fmaf(pr[v + 1], f[(v + 1) * NC + c], a1);
    a2 = fmaf(pr[v + 2], f[(v + 2) * NC + c], a2);
    a3 = fmaf(pr[v + 3], f[(v + 3) * NC + c], a3);
  }
  o[row * NC + c] = (a0 + a1) + (a2 + a3);
}

// ---------------- X = inv(Mx) via Gauss-Jordan w/ partial pivoting ----------------
__global__ __launch_bounds__(256) void invert_kernel(const float* Mx, float* X) {
  __shared__ float M[64][130];
  __shared__ float mult[64];
  __shared__ int piv;
  int tid = threadIdx.x;
  for (int e = tid; e < 4096; e += 256) {
    int r = e >> 6, c = e & 63;
    M[r][c] = Mx[e];
    M[r][64 + c] = (r == c) ? 1.f : 0.f;
  }
  __syncthreads();
  for (int k = 0; k < 64; ++k) {
    if (tid == 0) {
      int best = k; float bv = fabsf(M[k][k]);
      for (int r = k + 1; r < 64; ++r) { float v = fabsf(M[r][k]); if (v > bv) { bv = v; best = r; } }
      piv = best;
    }
    __syncthreads();
    if (piv != k) {
      for (int c = tid; c < 128; c += 256) { float t = M[k][c]; M[k][c] = M[piv][c]; M[piv][c] = t; }
    }
    __syncthreads();
    float pv = M[k][k];
    __syncthreads();
    float d = 1.f / pv;
    for (int c = tid; c < 128; c += 256) M[k][c] *= d;
    if (tid < 64) mult[tid] = (tid == k) ? 0.f : M[tid][k];
    __syncthreads();
    for (int e = tid; e < 8192; e += 256) {
      int r = e >> 7, c = e & 127;
      M[r][c] = fmaf(-mult[r], M[k][c], M[r][c]);
    }
    __syncthreads();
  }
  for (int e = tid; e < 4096; e += 256) X[e] = M[e >> 6][64 + (e & 63)];
}

// ---------------- resolvent scalar vectors ----------------
__global__ void scal_kernel(const float* ex, const float* ey,
                            float* r1r, float* r1i, float* r2r, float* r2i) {
  int t = threadIdx.x;  // 64 threads = 1 wave
  float vx = ex[t], vy = ey[t];
  float m = fmaxf(vx, vy);
#pragma unroll
  for (int o = 32; o > 0; o >>= 1) m = fmaxf(m, __shfl_xor(m, o, 64));
  float g1 = sqrtf(vx / m), g2 = sqrtf(vy / m);   // GAMMA = 0.5
  float d1 = 1.f / fmaf(g1, g1, 1.f), d2 = 1.f / fmaf(g2, g2, 1.f);
  r1r[t] = g1 * d1; r1i[t] = d1;
  r2r[t] = g2 * d2; r2i[t] = d2;
}

// ---------------- Bc = My @ B0 ----------------
__global__ __launch_bounds__(256) void bc_kernel(const float* My, const float* B0, float* Bc) {
  int idx = blockIdx.x * 256 + threadIdx.x;
  int i = idx >> 7, c = idx & 127;
  float acc = 0.f;
  for (int j = 0; j < 64; ++j) acc = fmaf(My[i * 64 + j], B0[j * NC + c], acc);
  Bc[idx] = acc;
}

// ---------------- small 64x64 products ----------------
__global__ __launch_bounds__(256) void smallmm_kernel(const float* A, const float* My, const float* X,
                                                      const float* r1r, const float* r1i, const float* Bc,
                                                      float* G, float* H, float* S0l, float* S1rl,
                                                      float* S1il, float* S2, float* Z) {
  int idx = blockIdx.x * 256 + threadIdx.x;
  int i = idx >> 6, j = idx & 63;
  int q = blockIdx.y;
  float acc = 0.f;
  if (q == 0) { for (int c = 0; c < 128; ++c) acc = fmaf(A[i * NC + c], A[j * NC + c], acc); G[idx] = acc; }
  else if (q == 1) { for (int t = 0; t < 64; ++t) acc = fmaf(My[t * 64 + i], My[t * 64 + j], acc); H[idx] = acc; }
  else if (q == 2) { for (int t = 0; t < 64; ++t) acc = fmaf(X[t * 64 + i], X[t * 64 + j], acc); S0l[idx] = LMBDA * acc; }
  else if (q == 3) { for (int t = 0; t < 64; ++t) acc = fmaf(r1r[t] * X[t * 64 + i], X[t * 64 + j], acc); S1rl[idx] = LMBDA * acc; }
  else if (q == 4) { for (int t = 0; t < 64; ++t) acc = fmaf(r1i[t] * X[t * 64 + i], X[t * 64 + j], acc); S1il[idx] = LMBDA * acc; }
  else if (q == 5) { for (int t = 0; t < 64; ++t) { float w2 = fmaf(r1r[t], r1r[t], r1i[t] * r1i[t]); acc = fmaf(w2 * X[t * 64 + i], X[t * 64 + j], acc); } S2[idx] = acc; }
  else { for (int c = 0; c < 128; ++c) acc = fmaf(A[i * NC + c], Bc[j * NC + c], acc); Z[idx] = acc; }
}

// ---------------- Rm = Z@My (rhs), W0 = G + lambda*S2 ----------------
__global__ __launch_bounds__(256) void rmw_kernel(const float* Z, const float* My, const float* G,
                                                  const float* S2, float* Rm, float* W0) {
  int idx = blockIdx.x * 256 + threadIdx.x;
  int i = idx >> 6, j = idx & 63;
  float acc = 0.f;
  for (int t = 0; t < 64; ++t) acc = fmaf(Z[i * 64 + t], My[t * 64 + j], acc);
  Rm[idx] = acc;
  W0[idx] = fmaf(LMBDA, S2[idx], G[idx]);
}

// ---------------- Q0 = DrHDr+DiHDi, Qr = DrH+HDr, Qi = DiH+HDi (entrywise) ----------------
__global__ void buildq_kernel(const float* H, const float* dr, const float* di,
                              float* Q0, float* Qr, float* Qi) {
  int e = blockIdx.x * 256 + threadIdx.x;
  int a = e >> 6, b = e & 63;
  float h = H[e];
  float dra = dr[a], drb = dr[b], dia = di[a], dib = di[b];
  Q0[e] = h * (dra * drb + dia * dib);
  Qr[e] = h * (dra + drb);
  Qi[e] = h * (dia + dib);
}

// ---------------- 64x64 Cholesky + explicit L^-1 (2 blocks: W0 and H) ----------------
__global__ __launch_bounds__(256) void chol64_kernel(const float* W0, const float* H,
                                                     float* LwI, float* LhI) {
  const float* src = blockIdx.x ? H : W0;
  float* dst = blockIdx.x ? LhI : LwI;
  __shared__ float M[64][65];
  __shared__ float T[64][65];
  int tid = threadIdx.x;
  for (int e = tid; e < 4096; e += 256) {
    int r = e >> 6, c = e & 63;
    M[r][c] = src[e];
    T[r][c] = 0.f;
  }
  __syncthreads();
  for (int j = 0; j < 64; ++j) {
    float pv = M[j][j];
    __syncthreads();
    float sc = rsqrtf(pv);
    if (tid < 64 - j) M[j + tid][j] *= sc;
    __syncthreads();
    int m = 63 - j, cnt = (m * (m + 1)) >> 1;
    for (int e = tid; e < cnt; e += 256) {
      int rp = (int)((sqrtf(8.f * (float)e + 1.f) - 1.f) * 0.5f);
      while (((rp + 1) * (rp + 2)) >> 1 <= e) ++rp;
      while ((rp * (rp + 1)) >> 1 > e) --rp;
      int cp = e - ((rp * (rp + 1)) >> 1);
      int r = j + 1 + rp, c = j + 1 + cp;
      M[r][c] = fmaf(-M[r][j], M[c][j], M[r][c]);
    }
    __syncthreads();
  }
  if (tid < 64) {               // T = L^{-1}, one lane per column
    int c = tid;
    T[c][c] = 1.f / M[c][c];
    for (int r = c + 1; r < 64; ++r) {
      float s = 0.f;
      for (int t = c; t < r; ++t) s = fmaf(M[r][t], T[t][c], s);
      T[r][c] = -s / M[r][r];
    }
  }
  __syncthreads();
  for (int e = tid; e < 4096; e += 256) dst[e] = T[e >> 6][e & 63];
}

// ---------------- OUT = L1 * M * L2^T, 7 instances (one block each) ----------------
__global__ __launch_bounds__(256) void sandwich_kernel(const float* LwI, const float* LhI,
      const float* S0l, const float* S1rl, const float* S1il,
      const float* Q0, const float* Qr, const float* Qi, const float* Rm,
      float* So0, float* So1r, float* So1i, float* Qo0, float* Qor, float* Qoi, float* Bo) {
  const float *L1, *Mi, *L2; float* D;
  switch (blockIdx.x) {
    case 0: L1 = LwI; Mi = S0l;  L2 = LwI; D = So0;  break;
    case 1: L1 = LwI; Mi = S1rl; L2 = LwI; D = So1r; break;
    case 2: L1 = LwI; Mi = S1il; L2 = LwI; D = So1i; break;
    case 3: L1 = LhI; Mi = Q0;   L2 = LhI; D = Qo0;  break;
    case 4: L1 = LhI; Mi = Qr;   L2 = LhI; D = Qor;  break;
    case 5: L1 = LhI; Mi = Qi;   L2 = LhI; D = Qoi;  break;
    default: L1 = LwI; Mi = Rm;  L2 = LhI; D = Bo;   break;
  }
  __shared__ float Ms[64][65];
  __shared__ float Ts[64][65];
  int tid = threadIdx.x, lane = tid & 63, wv = tid >> 6;
  for (int e = tid; e < 4096; e += 256) Ms[e >> 6][e & 63] = Mi[e];
  __syncthreads();
  for (int u = 0; u < 16; ++u) {        // TMP = L1*M
    int i = wv * 16 + u;
    float acc = 0.f;
    for (int k = 0; k < 64; ++k) acc = fmaf(L1[i * 64 + k], Ms[k][lane], acc);
    Ts[i][lane] = acc;
  }
  __syncthreads();
  for (int u = 0; u < 16; ++u) {        // OUT = TMP*L2^T
    int i = wv * 16 + u;
    float acc = 0.f;
    for (int k = 0; k < 64; ++k) acc = fmaf(Ts[i][k], L2[lane * 64 + k], acc);
    D[i * 64 + lane] = acc;
  }
}

// ---------------- pack Rstk (right factors) / LcatT (left factors, transposed) ----------------
__global__ void buildcg_kernel(const float* Qt0, const float* Qtr, const float* Qti,
                               const float* St0, const float* St1r, const float* St1i,
                               float* Rstk, float* LcatT) {
  int e = blockIdx.x * 256 + threadIdx.x;   // 16384
  int rho = e >> 6, t = rho >> 6, a = rho & 63, b = e & 63;
  float rv, lv;
  if (t == 0) { rv = (a == b) ? 1.f : 0.f; lv = rv; }
  else if (t == 1) { rv = 0.5f * (Qt0[a * 64 + b] + Qt0[b * 64 + a]); lv = 0.5f * (St0[a * 64 + b] + St0[b * 64 + a]); }
  else if (t == 2) { rv = 0.5f * (Qtr[a * 64 + b] + Qtr[b * 64 + a]); lv = -0.5f * (St1r[a * 64 + b] + St1r[b * 64 + a]); }
  else { rv = 0.5f * (Qti[a * 64 + b] + Qti[b * 64 + a]); lv = -0.5f * (St1i[a * 64 + b] + St1i[b * 64 + a]); }
  Rstk[e] = rv;
  LcatT[e] = lv;
}

__global__ void initctrl_kernel(float* ctrl) {
  for (int e = threadIdx.x; e < 1024; e += 256) ctrl[e] = 0.f;
}

__device__ __forceinline__ void gbar(int* cnt, int target) {
  __syncthreads();
  if (threadIdx.x == 0) {
    __hip_atomic_fetch_add(cnt, 1, __ATOMIC_ACQ_REL, __HIP_MEMORY_SCOPE_AGENT);
    while (__hip_atomic_load(cnt, __ATOMIC_ACQUIRE, __HIP_MEMORY_SCOPE_AGENT) < target) {
      __builtin_amdgcn_s_sleep(2);
    }
  }
  __syncthreads();
}

__device__ __forceinline__ void red_atomic(float v, float* red, float* dst) {
  int tid = threadIdx.x;
  red[tid] = v;
  __syncthreads();
  if (tid < 128) red[tid] += red[tid + 128];
  __syncthreads();
  if (tid < 64) {
    float s = red[tid] + red[tid + 64];
#pragma unroll
    for (int o = 32; o > 0; o >>= 1) s += __shfl_down(s, o, 64);
    if (tid == 0) atomicAdd(dst, s);
  }
  __syncthreads();
}

// ---------------- persistent CG on transformed system (16 blocks) ----------------
__global__ __launch_bounds__(256) void cg_kernel(const float* Bt, const float* Rstk, const float* LcatT,
                                                 float* rg, float* yg, int* cnt, float* pqA, float* rrA) {
  __shared__ float pT[64][68];          // pT[col][row]
  __shared__ float Rown[4][4][64];      // [t][jl][m] = Rstk[(t*64+j0+jl)*64+m]
  __shared__ float Tt[4][256];          // [jl][t*64+k]
  __shared__ float red[256];
  __shared__ float scal[4];
  int tid = threadIdx.x, blk = blockIdx.x;
  int lane = tid & 63, wv = tid >> 6;
  int j0 = blk * 4;
  int jown = j0 + wv;                   // owned column; owned row = lane
  for (int e = tid; e < 1024; e += 256) {
    int t = e >> 8, jl = (e >> 6) & 3, m = e & 63;
    Rown[t][jl][m] = Rstk[(t * 64 + j0 + jl) * 64 + m];
  }
  // init p = b (row-major source -> pT[col][row])
  for (int u = 0; u < 16; ++u) {
    int g = u * 256 + tid;              // g = k*64+m
    pT[g & 63][g >> 6] = Bt[g];
  }
  // r global (col-major), written once by block 0
  if (blk == 0) {
    for (int u = 0; u < 16; ++u) {
      int g = u * 256 + tid;            // g = j*64+i
      rg[g] = Bt[(g & 63) * 64 + (g >> 6)];
    }
  }
  {
    float v = Bt[lane * 64 + jown];
    red_atomic(v * v, red, &rrA[0]);
  }
  int bt = 0;
  gbar(cnt, (++bt) * 16);
  float x_reg = 0.f, q_reg = 0.f;
  for (int it = 0; it < MAXIT; ++it) {
    if (tid == 0) {
      scal[0] = aload(&rrA[it]);
      scal[1] = (it == 0) ? 1.f : aload(&rrA[it - 1]);
      scal[2] = aload(&rrA[0]);
    }
    __syncthreads();
    float rrold = scal[0];
    if (it > 0 && rrold < 3e-11f * scal[2]) break;
    float beta = (it == 0) ? 0.f : rrold / scal[1];
    // phase A: p = r + beta*p (full, redundant per block)
    for (int u = 0; u < 16; ++u) {
      int g = u * 256 + tid;            // col-major: j = g>>6, i = g&63
      float rv = aload(&rg[g]);
      pT[g >> 6][g & 63] = rv + beta * pT[g >> 6][g & 63];
    }
    __syncthreads();
    // stage1: T[(t=wv,k=lane)][j0+jl] = sum_m p[k][m] * Rstk_t[j][m]
    {
      float a0 = 0.f, a1 = 0.f, a2 = 0.f, a3 = 0.f;
      for (int m = 0; m < 64; ++m) {
        float pv = pT[m][lane];
        a0 = fmaf(pv, Rown[wv][0][m], a0);
        a1 = fmaf(pv, Rown[wv][1][m], a1);
        a2 = fmaf(pv, Rown[wv][2][m], a2);
        a3 = fmaf(pv, Rown[wv][3][m], a3);
      }
      Tt[0][wv * 64 + lane] = a0;
      Tt[1][wv * 64 + lane] = a1;
      Tt[2][wv * 64 + lane] = a2;
      Tt[3][wv * 64 + lane] = a3;
    }
    __syncthreads();
    // stage2: q[i=lane][j0+wv] = sum_tk LcatT[tk][i] * Tt[wv][tk]
    {
      const float* Lc = LcatT + lane;
      float a0 = 0.f, a1 = 0.f, a2 = 0.f, a3 = 0.f;
      for (int tk = 0; tk < 256; tk += 4) {
        a0 = fmaf(Lc[(tk + 0) * 64], Tt[wv][tk + 0], a0);
        a1 = fmaf(Lc[(tk + 1) * 64], Tt[wv][tk + 1], a1);
        a2 = fmaf(Lc[(tk + 2) * 64], Tt[wv][tk + 2], a2);
        a3 = fmaf(Lc[(tk + 3) * 64], Tt[wv][tk + 3], a3);
      }
      q_reg = (a0 + a1) + (a2 + a3);
    }
    red_atomic(pT[jown][lane] * q_reg, red, &pqA[it]);
    gbar(cnt, (++bt) * 16);
    if (tid == 0) scal[3] = aload(&pqA[it]);
    __syncthreads();
    float alpha = rrold / scal[3];
    x_reg = fmaf(alpha, pT[jown][lane], x_reg);
    float r_el = aload(&rg[jown * 64 + lane]) - alpha * q_reg;
    astore(&rg[jown * 64 + lane], r_el);
    red_atomic(r_el * r_el, red, &rrA[it + 1]);
    gbar(cnt, (++bt) * 16);
  }
  yg[jown * 64 + lane] = x_reg;         // y, col-major
}

// ---------------- out = C = (Lw^-T Y Lh^-1)^T = Lh^-T Y^T Lw^-1 ----------------
__global__ __launch_bounds__(256) void finish_kernel(const float* yg, const float* LwI,
                                                     const float* LhI, float* out) {
  __shared__ float Ys[64][65];   // Ys[j][k] = Y[k][j]
  __shared__ float Ts[64][65];
  int tid = threadIdx.x, lane = tid & 63, wv = tid >> 6;
  for (int e = tid; e < 4096; e += 256) Ys[e >> 6][e & 63] = yg[e];
  __syncthreads();
  for (int u = 0; u < 16; ++u) {        // TMP = Y^T * LwI
    int j = wv * 16 + u;
    float acc = 0.f;
    for (int k = 0; k < 64; ++k) acc = fmaf(Ys[j][k], LwI[k * 64 + lane], acc);
    Ts[j][lane] = acc;
  }
  __syncthreads();
  for (int u = 0; u < 16; ++u) {        // out = LhI^T * TMP
    int r = wv * 16 + u;
    float acc = 0.f;
    for (int m = 0; m < 64; ++m) acc = fmaf(LhI[m * 64 + r], Ts[m][lane], acc);
    out[r * 64 + lane] = acc;
  }
}

extern "C" void kernel_launch(void* const* d_in, const int* in_sizes, int n_in,
                              void* d_out, int out_size, void* d_ws, size_t ws_size,
                              hipStream_t stream) {
  const float* fx = (const float*)d_in[0];
  const float* fy = (const float*)d_in[1];
  const float* ex = (const float*)d_in[2];
  const float* ey = (const float*)d_in[3];
  const float* Px = (const float*)d_in[4];
  const float* Py = (const float*)d_in[5];
  const float* Mx = (const float*)d_in[6];
  const float* My = (const float*)d_in[7];
  float* out = (float*)d_out;
  float* W = (float*)d_ws;

  if (ws_size < (size_t)WS_NEED * sizeof(float)) {
    hipMemsetAsync(d_out, 0, (size_t)out_size * sizeof(float), stream);
    return;
  }

  float* Ap = W + A_OFF;    float* B0 = W + B0_OFF;  float* Bc = W + BC_OFF;
  float* Xp = W + X_OFF;
  float* r1r = W + R1R_OFF; float* r1i = W + R1I_OFF;
  float* r2r = W + R2R_OFF; float* r2i = W + R2I_OFF;
  float* G = W + G_OFF;     float* H = W + H_OFF;
  float* S0l = W + S0_OFF;  float* S1rl = W + S1R_OFF; float* S1il = W + S1I_OFF;
  float* S2 = W + S2_OFF;   float* W0 = W + W0_OFF;
  float* Z = W + Z_OFF;     float* Rm = W + RM_OFF;
  float* Q0 = W + Q0_OFF;   float* Qr = W + QR_OFF;   float* Qi = W + QI_OFF;
  float* LwI = W + LWI_OFF; float* LhI = W + LHI_OFF;
  float* St0 = W + ST0_OFF; float* St1r = W + ST1R_OFF; float* St1i = W + ST1I_OFF;
  float* Qt0 = W + QT0_OFF; float* Qtr = W + QTR_OFF; float* Qti = W + QTI_OFF;
  float* Bt = W + BT_OFF;
  float* Rstk = W + RSTK_OFF; float* LcT = W + LCT_OFF;
  float* rg = W + RG_OFF;   float* yg = W + YG_OFF;
  int* cnt = (int*)(W + CNT_OFF);
  float* pqA = W + PQ_OFF;  float* rrA = W + RR_OFF;

  dim3 gProj(64, 2);
  proj_kernel<<<gProj, 128, 0, stream>>>(Px, fx, Py, fy, Ap, B0);
  invert_kernel<<<1, 256, 0, stream>>>(Mx, Xp);
  scal_kernel<<<1, 64, 0, stream>>>(ex, ey, r1r, r1i, r2r, r2i);
  bc_kernel<<<32, 256, 0, stream>>>(My, B0, Bc);
  dim3 gSm(16, 7);
  smallmm_kernel<<<gSm, 256, 0, stream>>>(Ap, My, Xp, r1r, r1i, Bc, G, H, S0l, S1rl, S1il, S2, Z);
  rmw_kernel<<<16, 256, 0, stream>>>(Z, My, G, S2, Rm, W0);
  buildq_kernel<<<16, 256, 0, stream>>>(H, r2r, r2i, Q0, Qr, Qi);
  chol64_kernel<<<2, 256, 0, stream>>>(W0, H, LwI, LhI);
  sandwich_kernel<<<7, 256, 0, stream>>>(LwI, LhI, S0l, S1rl, S1il, Q0, Qr, Qi, Rm,
                                         St0, St1r, St1i, Qt0, Qtr, Qti, Bt);
  buildcg_kernel<<<64, 256, 0, stream>>>(Qt0, Qtr, Qti, St0, St1r, St1i, Rstk, LcT);
  initctrl_kernel<<<1, 256, 0, stream>>>(W + CNT_OFF);
  cg_kernel<<<16, 256, 0, stream>>>(Bt, Rstk, LcT, rg, yg, cnt, pqA, rrA);
  finish_kernel<<<1, 256, 0, stream>>>(yg, LwI, LhI, out);
}